// Round 4
// baseline (256.664 us; speedup 1.0000x reference)
//
#include <hip/hip_runtime.h>
#include <hip/hip_bf16.h>

#define NB_ 16      // batches
#define LA_ 1024
#define LB_ 1024
#define H_  512

typedef __attribute__((ext_vector_type(8))) short short8;   // 8 bf16 = 4 VGPRs
typedef __attribute__((ext_vector_type(4))) float f32x4;    // MFMA C/D

using bf16 = __hip_bfloat16;

__device__ __forceinline__ float bf2f(unsigned short u) {
    union { unsigned int i; float f; } c; c.i = ((unsigned)u) << 16; return c.f;
}
__device__ __forceinline__ unsigned short f2bf(float f) {
    bf16 h = __float2bfloat16(f);
    return *(unsigned short*)&h;
}

__device__ __forceinline__ void load_lds16(const void* g, void* l) {
    __builtin_amdgcn_global_load_lds(
        (const __attribute__((address_space(1))) void*)g,
        (__attribute__((address_space(3))) void*)l, 16, 0, 0);
}

// ---------------------------------------------------------------------------
// MFMA GEMM core, BK=32, explicit 2-stage double buffer, ONE barrier/iter:
//   iter k: barrier (drains tile-k loads, fences prev compute) ->
//           issue tile-k+1 loads into other buffer -> compute tile k.
// Each load batch gets a full compute phase in flight before its drain.
// LDS: 32 KB = [A0 8K][B0 8K][A1 8K][B1 8K]. Tile 128 rows x 32 bf16 (64 B
// rows = 4 x 16B chunks), chunk swizzle c ^ ((row>>1)&3) -> 2-way (free).
// 4 waves, 64x64 quadrant each, 4x4 fragments of 16x16x32.
// ---------------------------------------------------------------------------
__device__ __forceinline__ void gemm_core32(
    const unsigned short* __restrict__ A, const unsigned short* __restrict__ B,
    int lda, int ldb, int K,
    unsigned short* lds, f32x4 acc[4][4])
{
    const int t = threadIdx.x;
    const int wave = t >> 6, lane = t & 63;
    const int wr = wave >> 1, wc = wave & 1;
    const int lm = lane & 15, q = lane >> 4;

    // fragment LDS byte offsets within a stage (A at +0, B at +8192)
    int aoff[4], boff[4];
#pragma unroll
    for (int f = 0; f < 4; f++) {
        const int ra = wr * 64 + f * 16 + lm;
        aoff[f] = ra * 64 + ((q ^ ((ra >> 1) & 3)) << 4);
        const int rb = wc * 64 + f * 16 + lm;
        boff[f] = rb * 64 + ((q ^ ((rb >> 1) & 3)) << 4) + 8192;
    }

    // staging: wave covers rows wave*32..+31 in two 16-row instructions.
    // lane = r4*4 + pc; LDS slot chunk pc holds global chunk pc^((r4>>1)&3).
    const int r4 = lane >> 2, pc = lane & 3;
    const int srcc = pc ^ ((r4 >> 1) & 3);
    const unsigned short* gA0 = A + (size_t)(wave * 32 + r4) * lda + srcc * 8;
    const unsigned short* gA1 = gA0 + 16 * lda;
    const unsigned short* gB0 = B + (size_t)(wave * 32 + r4) * ldb + srcc * 8;
    const unsigned short* gB1 = gB0 + 16 * ldb;
    char* lwA = (char*)lds + wave * 2048;          // wave-uniform dst
    char* lwB = (char*)lds + 8192 + wave * 2048;

    // prologue: tile 0 -> stage 0
    load_lds16(gA0, lwA);
    load_lds16(gA1, lwA + 1024);
    load_lds16(gB0, lwB);
    load_lds16(gB1, lwB + 1024);

    int bo = 0;                                    // current stage byte offset
    for (int k0 = 0; k0 < K; k0 += 32) {
        __syncthreads();                           // tile k ready; prev reads done
        if (k0 + 32 < K) {
            const int nb = bo ^ 16384;
            load_lds16(gA0 + k0 + 32, lwA + nb);
            load_lds16(gA1 + k0 + 32, lwA + nb + 1024);
            load_lds16(gB0 + k0 + 32, lwB + nb);
            load_lds16(gB1 + k0 + 32, lwB + nb + 1024);
        }
        const char* base = (const char*)lds + bo;
        short8 av[4];
#pragma unroll
        for (int fm = 0; fm < 4; fm++)
            av[fm] = *(const short8*)(base + aoff[fm]);
#pragma unroll
        for (int fn = 0; fn < 4; fn++) {
            const short8 bv = *(const short8*)(base + boff[fn]);
#pragma unroll
            for (int fm = 0; fm < 4; fm++)
                acc[fm][fn] = __builtin_amdgcn_mfma_f32_16x16x32_bf16(
                    av[fm], bv, acc[fm][fn], 0, 0, 0);
        }
        bo ^= 16384;
    }
}

// ---------------------------------------------------------------------------
// GEMM1: S = a.b^T * temp; E = mask ? exp(S) : 0. Writes packed E (via LDS
// transpose) and packed ET (from regs), plus atomic l_row / l_col partials.
// ---------------------------------------------------------------------------
__global__ __launch_bounds__(256) void k_gemm_attn(
    const unsigned short* __restrict__ a_bf, const unsigned short* __restrict__ b_bf,
    const int* __restrict__ mask_a, const int* __restrict__ mask_b,
    const float* __restrict__ temp_p,
    unsigned short* __restrict__ E, unsigned short* __restrict__ ET,
    float* __restrict__ l_row, float* __restrict__ l_col)
{
    __shared__ unsigned short lds[16384];          // 32 KB: staging, then E tile

    const int batch = blockIdx.z;
    const int i0 = blockIdx.y * 128, j0 = blockIdx.x * 128;
    const unsigned short* A = a_bf + (size_t)batch * LA_ * H_ + (size_t)i0 * H_;
    const unsigned short* B = b_bf + (size_t)batch * LB_ * H_ + (size_t)j0 * H_;
    f32x4 acc[4][4];
#pragma unroll
    for (int x = 0; x < 4; x++)
#pragma unroll
        for (int y = 0; y < 4; y++) acc[x][y] = 0;

    gemm_core32(A, B, H_, H_, H_, lds, acc);

    const float temp = temp_p[0];
    const int t = threadIdx.x, wave = t >> 6, lane = t & 63;
    const int wr = wave >> 1, wc = wave & 1, lm = lane & 15, q = lane >> 4;
    const int* map = mask_a + batch * LA_;
    const int* mbp = mask_b + batch * LB_;
    unsigned short* Ep  = E  + (size_t)batch * LA_ * LB_;
    unsigned short* ETp = ET + (size_t)batch * LB_ * LA_;
    float* lrp = l_row + batch * LA_;
    float* lcp = l_col + batch * LB_;

    int mb[4];
#pragma unroll
    for (int fn = 0; fn < 4; fn++) mb[fn] = mbp[j0 + wc * 64 + fn * 16 + lm];

    // transform acc -> e (in place) and store packed ET rows from regs
#pragma unroll
    for (int fm = 0; fm < 4; fm++) {
        const int ib = i0 + wr * 64 + fm * 16 + q * 4;
        int ma[4];
#pragma unroll
        for (int r = 0; r < 4; r++) ma[r] = map[ib + r];
#pragma unroll
        for (int fn = 0; fn < 4; fn++) {
            const int j = j0 + wc * 64 + fn * 16 + lm;
            ushort4 pk;
            unsigned short* pp = (unsigned short*)&pk;
#pragma unroll
            for (int r = 0; r < 4; r++) {
                const float e = (ma[r] && mb[fn]) ? __expf(acc[fm][fn][r] * temp) : 0.0f;
                acc[fm][fn][r] = e;
                pp[r] = f2bf(e);
            }
            *(ushort4*)(ETp + (size_t)j * LA_ + ib) = pk;
        }
    }

    // l_row partials: sum over this block's 128 j's
#pragma unroll
    for (int fm = 0; fm < 4; fm++)
#pragma unroll
        for (int r = 0; r < 4; r++) {
            float s = acc[fm][0][r] + acc[fm][1][r] + acc[fm][2][r] + acc[fm][3][r];
            s += __shfl_xor(s, 1, 16); s += __shfl_xor(s, 2, 16);
            s += __shfl_xor(s, 4, 16); s += __shfl_xor(s, 8, 16);
            if (lm == 0) atomicAdd(&lrp[i0 + wr * 64 + fm * 16 + q * 4 + r], s);
        }
    // l_col partials: sum over this block's 128 i's
#pragma unroll
    for (int fn = 0; fn < 4; fn++) {
        float s = 0.0f;
#pragma unroll
        for (int fm = 0; fm < 4; fm++)
#pragma unroll
            for (int r = 0; r < 4; r++) s += acc[fm][fn][r];
        s += __shfl_xor(s, 16, 64); s += __shfl_xor(s, 32, 64);
        if (lane < 16) atomicAdd(&lcp[j0 + wc * 64 + fn * 16 + lm], s);
    }

    // packed E via swizzled LDS transpose (reuse staging LDS)
    __syncthreads();
#pragma unroll
    for (int fm = 0; fm < 4; fm++)
#pragma unroll
        for (int fn = 0; fn < 4; fn++)
#pragma unroll
            for (int r = 0; r < 4; r++) {
                const int il = wr * 64 + fm * 16 + q * 4 + r;
                const int jl = wc * 64 + fn * 16 + lm;
                lds[il * 128 + (((jl >> 3) ^ ((il >> 1) & 7)) << 3) + (jl & 7)] =
                    f2bf(acc[fm][fn][r]);
            }
    __syncthreads();
#pragma unroll
    for (int rep = 0; rep < 8; rep++) {
        const int il = (t >> 4) + rep * 16;
        const int jc = t & 15;
        const int phys = jc ^ ((il >> 1) & 7);
        short8 v = *(const short8*)(lds + il * 128 + phys * 8);
        *(short8*)(Ep + (size_t)(i0 + il) * LB_ + j0 + jc * 8) = v;
    }
}

// ---------------------------------------------------------------------------
// GEMM2+3 merged: z<16 -> feature_a (E . bT^T), z>=16 -> feature_b (ET . aT^T)
// out = rownorm(Amat . Bm^T) with fallback to meanv for invalid rows.
// ---------------------------------------------------------------------------
__global__ __launch_bounds__(256) void k_gemm_feat(
    const unsigned short* __restrict__ E, const unsigned short* __restrict__ ET,
    const unsigned short* __restrict__ aT, const unsigned short* __restrict__ bT,
    const int* __restrict__ mask_a, const int* __restrict__ mask_b,
    const int* __restrict__ nA, const int* __restrict__ nB,
    const float* __restrict__ l_row, const float* __restrict__ l_col,
    const float* __restrict__ mean_a, const float* __restrict__ mean_b,
    float* __restrict__ out)
{
    __shared__ unsigned short lds[16384];

    const int z = blockIdx.z;
    const int batch = z & 15;
    const bool isA = z < 16;
    const unsigned short* Amat = (isA ? E : ET) + (size_t)batch * 1024 * 1024;
    const unsigned short* Bm   = (isA ? bT : aT) + (size_t)batch * H_ * 1024;
    const int* mp   = (isA ? mask_a : mask_b) + batch * 1024;
    const int nn    = (isA ? nB : nA)[batch];
    const float* sp = (isA ? l_row : l_col) + batch * 1024;
    const float* mv = (isA ? mean_b : mean_a) + batch * H_;
    float* op = out + (isA ? (size_t)0 : (size_t)NB_ * LA_ * H_) + (size_t)batch * 1024 * H_;

    const int m0 = blockIdx.y * 128, n0 = blockIdx.x * 128;
    f32x4 acc[4][4];
#pragma unroll
    for (int x = 0; x < 4; x++)
#pragma unroll
        for (int y = 0; y < 4; y++) acc[x][y] = 0;

    gemm_core32(Amat + (size_t)m0 * 1024, Bm + (size_t)n0 * 1024,
                1024, 1024, 1024, lds, acc);

    const int t = threadIdx.x, wave = t >> 6, lane = t & 63;
    const int wr = wave >> 1, wc = wave & 1, lm = lane & 15, q = lane >> 4;

    float mval[4];
#pragma unroll
    for (int fn = 0; fn < 4; fn++) mval[fn] = mv[n0 + wc * 64 + fn * 16 + lm];

#pragma unroll
    for (int fm = 0; fm < 4; fm++) {
        const int ib = m0 + wr * 64 + fm * 16 + q * 4;
#pragma unroll
        for (int r = 0; r < 4; r++) {
            const int i = ib + r;
            const bool valid = (mp[i] != 0) && (nn > 0);
            const float inv = valid ? 1.0f / sp[i] : 0.0f;
#pragma unroll
            for (int fn = 0; fn < 4; fn++) {
                const int d = n0 + wc * 64 + fn * 16 + lm;
                op[(size_t)i * H_ + d] = valid ? acc[fm][fn][r] * inv : mval[fn];
            }
        }
    }
}

// ---------------------------------------------------------------------------
// prep (a and b merged): fp32 [1024][512] -> bf16 [1024][512] + bf16^T
// [512][1024], plus atomic per-batch column-mean partials.
// ---------------------------------------------------------------------------
__global__ __launch_bounds__(256) void k_prep(
    const float* __restrict__ a, const float* __restrict__ b,
    unsigned short* __restrict__ aN, unsigned short* __restrict__ bN,
    unsigned short* __restrict__ aT, unsigned short* __restrict__ bT,
    float* __restrict__ mean_a, float* __restrict__ mean_b)
{
    __shared__ unsigned short lds[64][68];
    __shared__ float smean[64];
    const int z = blockIdx.z;
    const int batch = z & 15, sel = z >> 4;
    const float* src = sel ? b : a;
    unsigned short* np = (sel ? bN : aN) + (size_t)batch * 1024 * H_;
    unsigned short* tp = (sel ? bT : aT) + (size_t)batch * H_ * 1024;
    float* mdst = (sel ? mean_b : mean_a) + batch * H_;
    const float* sp = src + (size_t)batch * 1024 * H_;

    const int d0 = blockIdx.x * 64, i0 = blockIdx.y * 64;
    const int t = threadIdx.x;
    if (t < 64) smean[t] = 0.0f;
    const int c4 = (t & 15) * 4;
#pragma unroll
    for (int it = 0; it < 4; it++) {
        const int r = (t >> 4) + it * 16;
        float4 v = *(const float4*)(sp + (size_t)(i0 + r) * H_ + d0 + c4);
        ushort4 u = make_ushort4(f2bf(v.x), f2bf(v.y), f2bf(v.z), f2bf(v.w));
        *(ushort4*)(np + (size_t)(i0 + r) * H_ + d0 + c4) = u;
        *(ushort4*)&lds[r][c4] = u;
    }
    __syncthreads();
#pragma unroll
    for (int it = 0; it < 4; it++) {
        const int dd = (t >> 4) + it * 16;
        const int i4 = (t & 15) * 4;
        ushort4 u = make_ushort4(lds[i4][dd], lds[i4 + 1][dd], lds[i4 + 2][dd], lds[i4 + 3][dd]);
        *(ushort4*)(tp + (size_t)(d0 + dd) * 1024 + i0 + i4) = u;
        atomicAdd(&smean[dd], bf2f(u.x) + bf2f(u.y) + bf2f(u.z) + bf2f(u.w));
    }
    __syncthreads();
    if (t < 64) atomicAdd(&mdst[d0 + t], smean[t] * (1.0f / 1024.0f));
}

// ---------------------------------------------------------------------------
// mask token counts per batch
// ---------------------------------------------------------------------------
__global__ __launch_bounds__(256) void k_count(const int* __restrict__ mask_a,
                                               const int* __restrict__ mask_b,
                                               int* __restrict__ nA, int* __restrict__ nB)
{
    const int batch = blockIdx.x, t = threadIdx.x;
    int sa = 0, sb = 0;
    for (int i = t; i < 1024; i += 256) {
        sa += mask_a[batch * 1024 + i];
        sb += mask_b[batch * 1024 + i];
    }
    __shared__ int ra[256], rb[256];
    ra[t] = sa; rb[t] = sb;
    __syncthreads();
    for (int off = 128; off; off >>= 1) {
        if (t < off) { ra[t] += ra[t + off]; rb[t] += rb[t + off]; }
        __syncthreads();
    }
    if (t == 0) { nA[batch] = ra[0]; nB[batch] = rb[0]; }
}

// ---------------------------------------------------------------------------
extern "C" void kernel_launch(void* const* d_in, const int* in_sizes, int n_in,
                              void* d_out, int out_size, void* d_ws, size_t ws_size,
                              hipStream_t stream)
{
    const float* a      = (const float*)d_in[0];
    const float* b      = (const float*)d_in[1];
    const int*   mask_a = (const int*)d_in[2];
    const int*   mask_b = (const int*)d_in[3];
    const float* temp   = (const float*)d_in[4];
    float* out = (float*)d_out;

    // workspace layout (~128.2 MiB)
    char* ws = (char*)d_ws;
    size_t off = 0;
    unsigned short* E    = (unsigned short*)(ws + off); off += (size_t)NB_ * LA_ * LB_ * 2;  // 32 MiB
    unsigned short* ET   = (unsigned short*)(ws + off); off += (size_t)NB_ * LB_ * LA_ * 2;  // 32 MiB
    unsigned short* a_bf = (unsigned short*)(ws + off); off += (size_t)NB_ * LA_ * H_ * 2;   // 16 MiB
    unsigned short* b_bf = (unsigned short*)(ws + off); off += (size_t)NB_ * LB_ * H_ * 2;   // 16 MiB
    unsigned short* aT   = (unsigned short*)(ws + off); off += (size_t)NB_ * H_ * LA_ * 2;   // 16 MiB
    unsigned short* bT   = (unsigned short*)(ws + off); off += (size_t)NB_ * H_ * LB_ * 2;   // 16 MiB
    float* l_row  = (float*)(ws + off); off += (size_t)NB_ * LA_ * 4;   // zeroed region start
    float* l_col  = (float*)(ws + off); off += (size_t)NB_ * LB_ * 4;
    float* mean_a = (float*)(ws + off); off += (size_t)NB_ * H_ * 4;
    float* mean_b = (float*)(ws + off); off += (size_t)NB_ * H_ * 4;
    int*   nA     = (int*)(ws + off); off += 64;
    int*   nB     = (int*)(ws + off); off += 64;

    // zero the atomic accumulators (l_row, l_col, mean_a, mean_b contiguous)
    hipMemsetAsync(l_row, 0, (size_t)NB_ * (LA_ + LB_ + H_ + H_) * 4, stream);

    k_prep<<<dim3(H_ / 64, 1024 / 64, 32), 256, 0, stream>>>(
        a, b, a_bf, b_bf, aT, bT, mean_a, mean_b);
    k_count<<<dim3(NB_), 256, 0, stream>>>(mask_a, mask_b, nA, nB);

    k_gemm_attn<<<dim3(LB_ / 128, LA_ / 128, NB_), 256, 0, stream>>>(
        a_bf, b_bf, mask_a, mask_b, temp, E, ET, l_row, l_col);

    k_gemm_feat<<<dim3(H_ / 128, 1024 / 128, 32), 256, 0, stream>>>(
        E, ET, aT, bT, mask_a, mask_b, nA, nB, l_row, l_col, mean_a, mean_b, out);
}

// Round 5
// 227.274 us; speedup vs baseline: 1.1293x; 1.1293x over previous
//
#include <hip/hip_runtime.h>
#include <hip/hip_bf16.h>

#define NB_ 16      // batches
#define LA_ 1024
#define LB_ 1024
#define H_  512

typedef __attribute__((ext_vector_type(8))) short short8;   // 8 bf16 = 4 VGPRs
typedef __attribute__((ext_vector_type(4))) float f32x4;    // MFMA C/D

using bf16 = __hip_bfloat16;

__device__ __forceinline__ float bf2f(unsigned short u) {
    union { unsigned int i; float f; } c; c.i = ((unsigned)u) << 16; return c.f;
}
__device__ __forceinline__ unsigned short f2bf(float f) {
    bf16 h = __float2bfloat16(f);
    return *(unsigned short*)&h;
}

__device__ __forceinline__ void load_lds16(const void* g, void* l) {
    __builtin_amdgcn_global_load_lds(
        (const __attribute__((address_space(1))) void*)g,
        (__attribute__((address_space(3))) void*)l, 16, 0, 0);
}

// ---------------------------------------------------------------------------
// MFMA GEMM core, BK=64 (R3-proven): C(128x128) = A(128xK) . B^T(128xK),
// bf16, fp32 acc. LDS tiles [128][64] bf16 (128 B rows = 8 x 16B chunks);
// chunk XOR-swizzled by (row&7). 32 MFMA + 8 global_load_lds per barrier
// pair. 4 waves, 64x64 quadrant each, 4x4 fragments.
// ---------------------------------------------------------------------------
__device__ __forceinline__ void gemm_core64(
    const unsigned short* __restrict__ A, const unsigned short* __restrict__ B,
    int lda, int ldb, int K,
    unsigned short* ldsA, unsigned short* ldsB, f32x4 acc[4][4])
{
    const int t = threadIdx.x;
    const int wave = t >> 6, lane = t & 63;
    const int wr = wave >> 1, wc = wave & 1;
    const int lm = lane & 15, q = lane >> 4;

    // fragment LDS byte offsets for kk=0; kk=1 is addr ^ 64 (chunk bit2 flip)
    int aoff[4], boff[4];
#pragma unroll
    for (int f = 0; f < 4; f++) {
        const int ra = wr * 64 + f * 16 + lm;
        aoff[f] = ra * 128 + ((q ^ (ra & 7)) << 4);
        const int rb = wc * 64 + f * 16 + lm;
        boff[f] = rb * 128 + ((q ^ (rb & 7)) << 4);
    }

    // staging: instr s covers rows (s*4+wave)*8 .. +7; lane = r8*8 + c;
    // LDS slot chunk c holds global chunk c ^ (row&7); row&7 is s-invariant.
    const int row0 = wave * 8 + (lane >> 3);
    const int sc = (lane & 7) ^ (row0 & 7);
    const unsigned short* gA0 = A + (size_t)row0 * lda + sc * 8;
    const unsigned short* gB0 = B + (size_t)row0 * ldb + sc * 8;
    const int sA = 32 * lda, sB = 32 * ldb;      // shorts per s-step
    char* lA = (char*)ldsA + wave * 1024;        // wave-uniform LDS dst
    char* lB = (char*)ldsB + wave * 1024;

    for (int k0 = 0; k0 < K; k0 += 64) {
        __syncthreads();                         // protect LDS from prev-iter reads
#pragma unroll
        for (int s = 0; s < 4; s++) {
            load_lds16(gA0 + k0 + s * sA, lA + s * 4096);
            load_lds16(gB0 + k0 + s * sB, lB + s * 4096);
        }
        __syncthreads();                         // drains vmcnt before reads
#pragma unroll
        for (int kk = 0; kk < 2; kk++) {
            const int kx = kk << 6;
            short8 av[4];
#pragma unroll
            for (int fm = 0; fm < 4; fm++)
                av[fm] = *(const short8*)((const char*)ldsA + (aoff[fm] ^ kx));
#pragma unroll
            for (int fn = 0; fn < 4; fn++) {
                const short8 bv = *(const short8*)((const char*)ldsB + (boff[fn] ^ kx));
#pragma unroll
                for (int fm = 0; fm < 4; fm++)
                    acc[fm][fn] = __builtin_amdgcn_mfma_f32_16x16x32_bf16(
                        av[fm], bv, acc[fm][fn], 0, 0, 0);
            }
        }
    }
}

// ---------------------------------------------------------------------------
// GEMM1: S = a.b^T * temp; E = mask ? exp(S) : 0. Writes packed E (via LDS
// transpose) and packed ET (from regs), plus atomic l_row / l_col partials.
// Grid: 1D, 1024 blocks, g = q*16 + batch so all 64 blocks of one batch map
// to XCD batch%8 (L2 locality: a/b panels fetched ~once per XCD).
// ---------------------------------------------------------------------------
__global__ __launch_bounds__(256) void k_gemm_attn(
    const unsigned short* __restrict__ a_bf, const unsigned short* __restrict__ b_bf,
    const int* __restrict__ mask_a, const int* __restrict__ mask_b,
    const float* __restrict__ temp_p,
    unsigned short* __restrict__ E, unsigned short* __restrict__ ET,
    float* __restrict__ l_row, float* __restrict__ l_col)
{
    __shared__ unsigned short lds[16384];        // 32 KB: staging, then E tile
    unsigned short* ldsA = lds;
    unsigned short* ldsB = lds + 8192;

    const int g = blockIdx.x;
    const int batch = g & 15;
    const int qq = g >> 4;                       // 0..63
    const int i0 = (qq >> 3) * 128, j0 = (qq & 7) * 128;

    const unsigned short* A = a_bf + (size_t)batch * LA_ * H_ + (size_t)i0 * H_;
    const unsigned short* B = b_bf + (size_t)batch * LB_ * H_ + (size_t)j0 * H_;
    f32x4 acc[4][4];
#pragma unroll
    for (int x = 0; x < 4; x++)
#pragma unroll
        for (int y = 0; y < 4; y++) acc[x][y] = 0;

    gemm_core64(A, B, H_, H_, H_, ldsA, ldsB, acc);

    const float temp = temp_p[0];
    const int t = threadIdx.x, wave = t >> 6, lane = t & 63;
    const int wr = wave >> 1, wc = wave & 1, lm = lane & 15, q = lane >> 4;
    const int* map = mask_a + batch * LA_;
    const int* mbp = mask_b + batch * LB_;
    unsigned short* Ep  = E  + (size_t)batch * LA_ * LB_;
    unsigned short* ETp = ET + (size_t)batch * LB_ * LA_;
    float* lrp = l_row + batch * LA_;
    float* lcp = l_col + batch * LB_;

    int mb[4];
#pragma unroll
    for (int fn = 0; fn < 4; fn++) mb[fn] = mbp[j0 + wc * 64 + fn * 16 + lm];

    // transform acc -> e (in place) and store packed ET rows from regs
#pragma unroll
    for (int fm = 0; fm < 4; fm++) {
        const int ib = i0 + wr * 64 + fm * 16 + q * 4;
        int ma[4];
#pragma unroll
        for (int r = 0; r < 4; r++) ma[r] = map[ib + r];
#pragma unroll
        for (int fn = 0; fn < 4; fn++) {
            const int j = j0 + wc * 64 + fn * 16 + lm;
            ushort4 pk;
            unsigned short* pp = (unsigned short*)&pk;
#pragma unroll
            for (int r = 0; r < 4; r++) {
                const float e = (ma[r] && mb[fn]) ? __expf(acc[fm][fn][r] * temp) : 0.0f;
                acc[fm][fn][r] = e;
                pp[r] = f2bf(e);
            }
            *(ushort4*)(ETp + (size_t)j * LA_ + ib) = pk;
        }
    }

    // l_row partials: sum over this block's 128 j's
#pragma unroll
    for (int fm = 0; fm < 4; fm++)
#pragma unroll
        for (int r = 0; r < 4; r++) {
            float s = acc[fm][0][r] + acc[fm][1][r] + acc[fm][2][r] + acc[fm][3][r];
            s += __shfl_xor(s, 1, 16); s += __shfl_xor(s, 2, 16);
            s += __shfl_xor(s, 4, 16); s += __shfl_xor(s, 8, 16);
            if (lm == 0) atomicAdd(&lrp[i0 + wr * 64 + fm * 16 + q * 4 + r], s);
        }
    // l_col partials: sum over this block's 128 i's
#pragma unroll
    for (int fn = 0; fn < 4; fn++) {
        float s = 0.0f;
#pragma unroll
        for (int fm = 0; fm < 4; fm++)
#pragma unroll
            for (int r = 0; r < 4; r++) s += acc[fm][fn][r];
        s += __shfl_xor(s, 16, 64); s += __shfl_xor(s, 32, 64);
        if (lane < 16) atomicAdd(&lcp[j0 + wc * 64 + fn * 16 + lm], s);
    }

    // packed E via swizzled LDS transpose (reuse staging LDS)
    __syncthreads();
#pragma unroll
    for (int fm = 0; fm < 4; fm++)
#pragma unroll
        for (int fn = 0; fn < 4; fn++)
#pragma unroll
            for (int r = 0; r < 4; r++) {
                const int il = wr * 64 + fm * 16 + q * 4 + r;
                const int jl = wc * 64 + fn * 16 + lm;
                lds[il * 128 + (((jl >> 3) ^ ((il >> 1) & 7)) << 3) + (jl & 7)] =
                    f2bf(acc[fm][fn][r]);
            }
    __syncthreads();
#pragma unroll
    for (int rep = 0; rep < 8; rep++) {
        const int il = (t >> 4) + rep * 16;
        const int jc = t & 15;
        const int phys = jc ^ ((il >> 1) & 7);
        short8 v = *(const short8*)(lds + il * 128 + phys * 8);
        *(short8*)(Ep + (size_t)(i0 + il) * LB_ + j0 + jc * 8) = v;
    }
}

// ---------------------------------------------------------------------------
// GEMM2+3 merged: zc<16 -> feature_a (E . bT^T), zc>=16 -> feature_b (ET.aT^T)
// Grid: 1D, 1024 blocks, g = q*32 + zc so all 32 blocks of one (batch,side)
// land on XCD zc%8 concurrently: A-tile shared by 4 n-blocks, B-panel by 8
// m-blocks, all in one 4MB L2 (working set ~3 MB).
// ---------------------------------------------------------------------------
__global__ __launch_bounds__(256) void k_gemm_feat(
    const unsigned short* __restrict__ E, const unsigned short* __restrict__ ET,
    const unsigned short* __restrict__ aT, const unsigned short* __restrict__ bT,
    const int* __restrict__ mask_a, const int* __restrict__ mask_b,
    const int* __restrict__ nA, const int* __restrict__ nB,
    const float* __restrict__ l_row, const float* __restrict__ l_col,
    const float* __restrict__ mean_a, const float* __restrict__ mean_b,
    float* __restrict__ out)
{
    __shared__ unsigned short lds[16384];
    unsigned short* ldsA = lds;
    unsigned short* ldsB = lds + 8192;

    const int g = blockIdx.x;
    const int zc = g & 31;
    const int qq = g >> 5;                       // 0..31
    const int n0 = (qq & 3) * 128, m0 = (qq >> 2) * 128;

    const int batch = zc & 15;
    const bool isA = zc < 16;
    const unsigned short* Amat = (isA ? E : ET) + (size_t)batch * 1024 * 1024;
    const unsigned short* Bm   = (isA ? bT : aT) + (size_t)batch * H_ * 1024;
    const int* mp   = (isA ? mask_a : mask_b) + batch * 1024;
    const int nn    = (isA ? nB : nA)[batch];
    const float* sp = (isA ? l_row : l_col) + batch * 1024;
    const float* mv = (isA ? mean_b : mean_a) + batch * H_;
    float* op = out + (isA ? (size_t)0 : (size_t)NB_ * LA_ * H_) + (size_t)batch * 1024 * H_;

    f32x4 acc[4][4];
#pragma unroll
    for (int x = 0; x < 4; x++)
#pragma unroll
        for (int y = 0; y < 4; y++) acc[x][y] = 0;

    gemm_core64(Amat + (size_t)m0 * 1024, Bm + (size_t)n0 * 1024,
                1024, 1024, 1024, ldsA, ldsB, acc);

    const int t = threadIdx.x, wave = t >> 6, lane = t & 63;
    const int wr = wave >> 1, wc = wave & 1, lm = lane & 15, q = lane >> 4;

    float mval[4];
#pragma unroll
    for (int fn = 0; fn < 4; fn++) mval[fn] = mv[n0 + wc * 64 + fn * 16 + lm];

#pragma unroll
    for (int fm = 0; fm < 4; fm++) {
        const int ib = m0 + wr * 64 + fm * 16 + q * 4;
#pragma unroll
        for (int r = 0; r < 4; r++) {
            const int i = ib + r;
            const bool valid = (mp[i] != 0) && (nn > 0);
            const float inv = valid ? 1.0f / sp[i] : 0.0f;
#pragma unroll
            for (int fn = 0; fn < 4; fn++) {
                const int d = n0 + wc * 64 + fn * 16 + lm;
                op[(size_t)i * H_ + d] = valid ? acc[fm][fn][r] * inv : mval[fn];
            }
        }
    }
}

// ---------------------------------------------------------------------------
// prep (a and b merged): fp32 [1024][512] -> bf16 [1024][512] + bf16^T
// [512][1024], plus atomic per-batch column-mean partials.
// ---------------------------------------------------------------------------
__global__ __launch_bounds__(256) void k_prep(
    const float* __restrict__ a, const float* __restrict__ b,
    unsigned short* __restrict__ aN, unsigned short* __restrict__ bN,
    unsigned short* __restrict__ aT, unsigned short* __restrict__ bT,
    float* __restrict__ mean_a, float* __restrict__ mean_b)
{
    __shared__ unsigned short lds[64][68];
    __shared__ float smean[64];
    const int z = blockIdx.z;
    const int batch = z & 15, sel = z >> 4;
    const float* src = sel ? b : a;
    unsigned short* np = (sel ? bN : aN) + (size_t)batch * 1024 * H_;
    unsigned short* tp = (sel ? bT : aT) + (size_t)batch * H_ * 1024;
    float* mdst = (sel ? mean_b : mean_a) + batch * H_;
    const float* sp = src + (size_t)batch * 1024 * H_;

    const int d0 = blockIdx.x * 64, i0 = blockIdx.y * 64;
    const int t = threadIdx.x;
    if (t < 64) smean[t] = 0.0f;
    const int c4 = (t & 15) * 4;
#pragma unroll
    for (int it = 0; it < 4; it++) {
        const int r = (t >> 4) + it * 16;
        float4 v = *(const float4*)(sp + (size_t)(i0 + r) * H_ + d0 + c4);
        ushort4 u = make_ushort4(f2bf(v.x), f2bf(v.y), f2bf(v.z), f2bf(v.w));
        *(ushort4*)(np + (size_t)(i0 + r) * H_ + d0 + c4) = u;
        *(ushort4*)&lds[r][c4] = u;
    }
    __syncthreads();
#pragma unroll
    for (int it = 0; it < 4; it++) {
        const int dd = (t >> 4) + it * 16;
        const int i4 = (t & 15) * 4;
        ushort4 u = make_ushort4(lds[i4][dd], lds[i4 + 1][dd], lds[i4 + 2][dd], lds[i4 + 3][dd]);
        *(ushort4*)(tp + (size_t)(d0 + dd) * 1024 + i0 + i4) = u;
        atomicAdd(&smean[dd], bf2f(u.x) + bf2f(u.y) + bf2f(u.z) + bf2f(u.w));
    }
    __syncthreads();
    if (t < 64) atomicAdd(&mdst[d0 + t], smean[t] * (1.0f / 1024.0f));
}

// ---------------------------------------------------------------------------
// init: blocks 0..47 zero the 49152-float accumulator region (l_row, l_col,
// mean_a, mean_b); blocks 48..79 compute per-batch mask counts.
// ---------------------------------------------------------------------------
__global__ __launch_bounds__(256) void k_init(
    float* __restrict__ accum_zero,              // 49152 floats
    const int* __restrict__ mask_a, const int* __restrict__ mask_b,
    int* __restrict__ nA, int* __restrict__ nB)
{
    const int g = blockIdx.x, t = threadIdx.x;
    if (g < 48) {
        *(float4*)(accum_zero + (size_t)(g * 256 + t) * 4) = make_float4(0, 0, 0, 0);
        return;
    }
    const int sel = g - 48;                      // 0..31
    const int batch = sel & 15, which = sel >> 4;
    const int* m = (which ? mask_b : mask_a) + batch * 1024;
    int s = m[t] + m[t + 256] + m[t + 512] + m[t + 768];
    __shared__ int red[256];
    red[t] = s;
    __syncthreads();
    for (int off = 128; off; off >>= 1) {
        if (t < off) red[t] += red[t + off];
        __syncthreads();
    }
    if (t == 0) (which ? nB : nA)[batch] = red[0];
}

// ---------------------------------------------------------------------------
extern "C" void kernel_launch(void* const* d_in, const int* in_sizes, int n_in,
                              void* d_out, int out_size, void* d_ws, size_t ws_size,
                              hipStream_t stream)
{
    const float* a      = (const float*)d_in[0];
    const float* b      = (const float*)d_in[1];
    const int*   mask_a = (const int*)d_in[2];
    const int*   mask_b = (const int*)d_in[3];
    const float* temp   = (const float*)d_in[4];
    float* out = (float*)d_out;

    // workspace layout (~128.2 MiB)
    char* ws = (char*)d_ws;
    size_t off = 0;
    unsigned short* E    = (unsigned short*)(ws + off); off += (size_t)NB_ * LA_ * LB_ * 2;  // 32 MiB
    unsigned short* ET   = (unsigned short*)(ws + off); off += (size_t)NB_ * LB_ * LA_ * 2;  // 32 MiB
    unsigned short* a_bf = (unsigned short*)(ws + off); off += (size_t)NB_ * LA_ * H_ * 2;   // 16 MiB
    unsigned short* b_bf = (unsigned short*)(ws + off); off += (size_t)NB_ * LB_ * H_ * 2;   // 16 MiB
    unsigned short* aT   = (unsigned short*)(ws + off); off += (size_t)NB_ * H_ * LA_ * 2;   // 16 MiB
    unsigned short* bT   = (unsigned short*)(ws + off); off += (size_t)NB_ * H_ * LB_ * 2;   // 16 MiB
    float* l_row  = (float*)(ws + off); off += (size_t)NB_ * LA_ * 4;   // zeroed region start
    float* l_col  = (float*)(ws + off); off += (size_t)NB_ * LB_ * 4;
    float* mean_a = (float*)(ws + off); off += (size_t)NB_ * H_ * 4;
    float* mean_b = (float*)(ws + off); off += (size_t)NB_ * H_ * 4;
    int*   nA     = (int*)(ws + off); off += 64;
    int*   nB     = (int*)(ws + off); off += 64;

    // init: zero accumulators + mask counts (replaces memset + k_count)
    k_init<<<dim3(80), 256, 0, stream>>>(l_row, mask_a, mask_b, nA, nB);

    k_prep<<<dim3(H_ / 64, 1024 / 64, 32), 256, 0, stream>>>(
        a, b, a_bf, b_bf, aT, bT, mean_a, mean_b);

    k_gemm_attn<<<dim3(1024), 256, 0, stream>>>(
        a_bf, b_bf, mask_a, mask_b, temp, E, ET, l_row, l_col);

    k_gemm_feat<<<dim3(1024), 256, 0, stream>>>(
        E, ET, aT, bT, mask_a, mask_b, nA, nB, l_row, l_col, mean_a, mean_b, out);
}